// Round 7
// baseline (353.762 us; speedup 1.0000x reference)
//
#include <hip/hip_runtime.h>
#include <hip/hip_bf16.h>

// BaseQVLayer, R19:
//   xb/yb = bf16(x/y)             (k_cvt, x+y merged)
//   xp = x@Wx+bx; yp = y@Wy+by    (k_proj + row-norms, deep core 64x64)
//   zT = Wg^T @ xp^T [512 x 8192] (k_zT, deep core 64x64)
//   At[j,i] = 2*(yp_j.xp_i)/(Dx_i+Dy_j)   (k_aff, deep core 128x128)
//   p0/p1 = At @ z split-K halves (k_agg, deep core 128x128)
//   out = relu(p0+p1+bg)                  (k_fin)
//
// R19 delta: RACE FIX. R18's absmax failure exposed a cross-wave cp16
// visibility race introduced in R17: waitvm is PER-WAVE, so
// [waitvm -> ldfrag] guarantees only the reading wave's OWN cp16s landed;
// other waves' writes to the slot may still be in flight. R17 passed by
// slack (~1000cyc/iter >> L2 latency); R18's short 8-MFMA iterations
// shrank the slack -> mild bf16 corruption (0.80). Sound invariant
// (R14's): every read of a freshly staged slot must be preceded by
// [each wave waits OWN cp16s] -> [barrier]. New per-iter schedule:
//   barrier1 -> stage(prv,t+R-1) -> MFMA(t) [pure-register]
//   -> waitvm(own t+1, counted) -> barrier2 -> sched_barrier(0) -> ldfrag(t+1)
// Prologue likewise gains waitvm -> barrier -> ldfrag(0). Slot-overwrite
// hazard: stage at iter t is after barrier1(t); last reads of that slot
// retired before each wave's MFMA(t-1), hence before barrier1(t). Cost:
// +1 s_barrier/K-step; MFMA burst stays pure-register (R17's k_agg win).
// Geometry keeps R18's occupancy experiment (untested due to the race):
// k_aff 128^2 RING=3 48KB lb(256,3) -> 3 blk/CU 12 waves, grid 4096
// bijective XCD map; k_proj/k_zT 64x64 RING=4 -> 4 blk/CU; k_agg as R17.
//
// Workspace 154.6 MB (unchanged): At [0,128 MB) with xb@0 / yb@16MB
// aliased; xpb 8 | ypb 8 | zT 8 | WxT 1 | WyT 1 | WgT .5 | Dx,Dy.
// p0/p1 alias xpb/ypb (dead after k_aff).

typedef __attribute__((ext_vector_type(8))) short bf16x8;
typedef __attribute__((ext_vector_type(4))) short bf16x4;
typedef __attribute__((ext_vector_type(4))) float f32x4;

__device__ __forceinline__ short f2b(float f) {
    unsigned int u = __builtin_bit_cast(unsigned int, f);
    unsigned int r = (u + 0x7fffu + ((u >> 16) & 1u)) >> 16;
    return (short)r;
}
__device__ __forceinline__ float b2f(short s) {
    unsigned int u = ((unsigned int)(unsigned short)s) << 16;
    return __builtin_bit_cast(float, u);
}

// async global->LDS, 16 B/lane. LDS dest = wave-uniform base + lane*16.
__device__ __forceinline__ void cp16(const void* g, void* l) {
    __builtin_amdgcn_global_load_lds(
        (const __attribute__((address_space(1))) void*)g,
        (__attribute__((address_space(3))) void*)l, 16, 0, 0);
}

template<int N>
__device__ __forceinline__ void waitvm() {
    if constexpr (N == 0)       asm volatile("s_waitcnt vmcnt(0)" ::: "memory");
    else if constexpr (N == 2)  asm volatile("s_waitcnt vmcnt(2)" ::: "memory");
    else if constexpr (N == 4)  asm volatile("s_waitcnt vmcnt(4)" ::: "memory");
    else if constexpr (N == 6)  asm volatile("s_waitcnt vmcnt(6)" ::: "memory");
    else if constexpr (N == 8)  asm volatile("s_waitcnt vmcnt(8)" ::: "memory");
    else if constexpr (N == 12) asm volatile("s_waitcnt vmcnt(12)" ::: "memory");
    else static_assert(N == 0, "unsupported vmcnt literal");
}

// granule slot permutation (R16; read-conflict-free, write side structural)
__device__ __forceinline__ int gslot(int c, int row) {
    return c ^ (row & 3) ^ ((row >> 2) & 3);
}

constexpr int EPI_XP = 0;  // +bias, store bf16, atomic row-norm
constexpr int EPI_BF = 1;  // store bf16 (zT, k_agg partials)
constexpr int EPI_AT = 2;  // dice scale (rcp), store bf16

// ===================== deep-pipelined core (all GEMMs) =====================
// 256 threads, waves 2x2: wave tile (TM/2) x (TN/2). BK=32, RING LDS slots,
// counted vmcnt, cp16 staged RING-1 tiles ahead, fragments prefetched ONE
// tile ahead. Read-side invariant: waitvm(own) -> s_barrier -> ds_read.
template<int EPI, int TM, int TN, int RING>
__device__ __forceinline__ void gemm_deep(
    const short* __restrict__ A, int lda,
    const short* __restrict__ Bt, int ldb,
    int N, int K, int bm, int bn, int kbase,
    const float* __restrict__ bias,
    short* __restrict__ outb,
    float* __restrict__ Dacc,
    const float* __restrict__ Drow, const float* __restrict__ Dcol)
{
    constexpr int FRM = TM / 32;           // frags per wave along m
    constexpr int FRN = TN / 32;           // frags per wave along n
    constexpr int CPA = TM * 4 / 256;      // cp16/thread for A tile
    constexpr int CPB = TN * 4 / 256;      // cp16/thread for B tile
    constexpr int CPT = CPA + CPB;
    __shared__ __align__(16) short As[RING][TM * 32];
    __shared__ __align__(16) short Bs[RING][TN * 32];

    const int tid  = threadIdx.x;
    const int wave = tid >> 6;
    const int lane = tid & 63;
    const int quad = lane >> 4;
    const int l15  = lane & 15;
    const int wm   = (wave >> 1) * (FRM * 16);
    const int wn   = (wave & 1) * (FRN * 16);
    const int nk   = K / 32;

    f32x4 acc[FRM][FRN];
#pragma unroll
    for (int i = 0; i < FRM; i++)
#pragma unroll
        for (int j = 0; j < FRN; j++) acc[i][j] = f32x4{0.f, 0.f, 0.f, 0.f};

    auto stage = [&](int slot, int t) {
        const int k0 = kbase + t * 32;
#pragma unroll
        for (int s = 0; s < CPA; s++) {
            const int seg = tid + 256 * s;
            const int row = seg >> 2, c8 = seg & 3;
            const int gg  = gslot(c8, row);
            cp16(&A[(size_t)(bm + row) * lda + k0 + gg * 8], &As[slot][seg * 8]);
        }
#pragma unroll
        for (int s = 0; s < CPB; s++) {
            const int seg = tid + 256 * s;
            const int row = seg >> 2, c8 = seg & 3;
            const int gg  = gslot(c8, row);
            cp16(&Bt[(size_t)(bn + row) * ldb + k0 + gg * 8], &Bs[slot][seg * 8]);
        }
    };

    bf16x8 a[FRM], b[FRN];
    auto ldfrag = [&](int slot) {
#pragma unroll
        for (int i = 0; i < FRM; i++) {
            const int row = wm + i * 16 + l15;
            a[i] = *(const bf16x8*)&As[slot][row * 32 + (gslot(quad, row) << 3)];
        }
#pragma unroll
        for (int j = 0; j < FRN; j++) {
            const int row = wn + j * 16 + l15;
            b[j] = *(const bf16x8*)&Bs[slot][row * 32 + (gslot(quad, row) << 3)];
        }
    };

#pragma unroll
    for (int p = 0; p < RING - 1; ++p) stage(p, p);   // cp16 prefill
    waitvm<(RING - 2) * CPT>();                        // OWN tile-0 cp16 done
    __builtin_amdgcn_s_barrier();                      // ALL waves' tile-0 done
    __builtin_amdgcn_sched_barrier(0);
    ldfrag(0);                                         // frags(0) in regs

    int cur = 0, prv = RING - 1;
    for (int t = 0; t < nk; ++t) {
        __builtin_amdgcn_s_barrier();   // barrier1: prior frag reads retired
        // slot prv == (t-1)%RING: all reads of it completed before each
        // wave's MFMA(t-1), hence before this barrier.
        if (t + RING - 1 < nk) stage(prv, t + RING - 1);

        __builtin_amdgcn_s_setprio(1);
#pragma unroll
        for (int i = 0; i < FRM; i++)
#pragma unroll
            for (int j = 0; j < FRN; j++)
                acc[i][j] = __builtin_amdgcn_mfma_f32_16x16x32_bf16(a[i], b[j], acc[i][j], 0, 0, 0);
        __builtin_amdgcn_s_setprio(0);

        if (t + 1 < nk) {
            // own cp16s for tile t+1 done when only stages for tiles > t+1
            // remain outstanding
            if constexpr (RING == 3) {
                if (t + 2 < nk) waitvm<CPT>(); else waitvm<0>();
            } else {
                if (t + 3 < nk)      waitvm<2 * CPT>();
                else if (t + 2 < nk) waitvm<CPT>();
                else                 waitvm<0>();
            }
            __builtin_amdgcn_s_barrier();     // barrier2: publish to all waves
            __builtin_amdgcn_sched_barrier(0);
            ldfrag((cur + 1 == RING) ? 0 : cur + 1);   // frags(t+1)
        }
        prv = cur;
        cur = (cur + 1 == RING) ? 0 : cur + 1;
    }

    // C/D layout: col = lane&15, row = quad*4 + r  [m89/m91]
#pragma unroll
    for (int im = 0; im < FRM; ++im) {
#pragma unroll
        for (int r = 0; r < 4; ++r) {
            const int gm = bm + wm + im * 16 + quad * 4 + r;
            if (EPI == EPI_XP) {
                float s = 0.f;
#pragma unroll
                for (int jn = 0; jn < FRN; ++jn) {
                    const int gn = bn + wn + jn * 16 + l15;
                    const float v = acc[im][jn][r] + bias[gn];
                    outb[(size_t)gm * N + gn] = f2b(v);
                    s += v * v;
                }
#pragma unroll
                for (int m = 1; m < 16; m <<= 1) s += __shfl_xor(s, m, 64);
                if (l15 == 0) atomicAdd(&Dacc[gm], s);
            } else if (EPI == EPI_AT) {
                const float dy = Drow[gm];
#pragma unroll
                for (int jn = 0; jn < FRN; ++jn) {
                    const int gn = bn + wn + jn * 16 + l15;
                    const float v = 2.f * acc[im][jn][r] * __builtin_amdgcn_rcpf(Dcol[gn] + dy);
                    outb[(size_t)gm * N + gn] = f2b(v);
                }
            } else {  // EPI_BF
#pragma unroll
                for (int jn = 0; jn < FRN; ++jn) {
                    const int gn = bn + wn + jn * 16 + l15;
                    outb[(size_t)gm * N + gn] = f2b(acc[im][jn][r]);
                }
            }
        }
    }
}

// xp/yp = x@W + b, row norms. tile 64x64, RING=4 (32 KB LDS, 4 blk/CU).
// grid(8, 128): x = n-tile (512/64), y = m-tile (8192/64).
__global__ __launch_bounds__(256, 4)
void k_proj(const short* __restrict__ A, const short* __restrict__ Bt,
            const float* __restrict__ bias, short* __restrict__ outb,
            float* __restrict__ Dacc)
{
    gemm_deep<EPI_XP, 64, 64, 4>(A, 1024, Bt, 1024, 512, 1024,
                                 blockIdx.y * 64, blockIdx.x * 64, 0,
                                 bias, outb, Dacc, nullptr, nullptr);
}

// zT = Wg^T @ xp^T [512 x 8192]. tile 64x64, RING=4, grid(128, 8), K=512.
__global__ __launch_bounds__(256, 4)
void k_zT(const short* __restrict__ WgT, const short* __restrict__ xpb,
          short* __restrict__ zT)
{
    gemm_deep<EPI_BF, 64, 64, 4>(WgT, 512, xpb, 512, 8192, 512,
                                 blockIdx.y * 64, blockIdx.x * 64, 0,
                                 nullptr, zT, nullptr, nullptr, nullptr);
}

// At[j,i]. flat grid 4096; tile 128x128 (wave 64x64), RING=3 (48 KB LDS,
// 3 blk/CU, 12 waves). XCD x owns j-band of 8 tiles (1 MB yp in L2);
// 8 consecutive blocks share one xp i-tile. Bijective map.
__global__ __launch_bounds__(256, 3)
void k_aff(const short* __restrict__ ypb, const short* __restrict__ xpb,
           short* __restrict__ At, const float* __restrict__ Dy,
           const float* __restrict__ Dx)
{
    const int flat = blockIdx.x;
    const int xcd = flat & 7;
    const int q   = flat >> 3;            // 0..511
    const int by  = xcd * 8 + (q & 7);    // 0..63  (j tiles of 128)
    const int bx  = q >> 3;               // 0..63  (i tiles of 128)
    gemm_deep<EPI_AT, 128, 128, 3>(ypb, 512, xpb, 512, 8192, 512,
                                   by * 128, bx * 128, 0,
                                   nullptr, At, nullptr, Dy, Dx);
}

// Split-K At@z partials. tile 128x128, RING=4 (64 KB LDS, 2 blk/CU; At from
// HBM -> 2-iter cp16 age), grid 512. Group = (bm,z): its 4 bn-blocks on one
// XCD so the 1 MB At slice is L2-shared; z-halves read disjoint At columns.
__global__ __launch_bounds__(256, 2)
void k_agg(const short* __restrict__ At, const short* __restrict__ zT,
           short* __restrict__ p0, short* __restrict__ p1)
{
    const int flat = blockIdx.x;
    const int xcd = flat & 7;
    const int q   = flat >> 3;            // 0..63 within XCD
    const int g   = xcd * 16 + (q >> 2);  // group 0..127 = (bm, z)
    const int bm  = (g >> 1) * 128;
    const int z   = g & 1;
    const int bn  = (q & 3) * 128;
    short* outb = z ? p1 : p0;
    gemm_deep<EPI_BF, 128, 128, 4>(At, 8192, zT, 8192, 512, 4096,
                                   bm, bn, z * 4096,
                                   nullptr, outb, nullptr, nullptr, nullptr);
}

// out = relu(p0 + p1 + bg). 8 elems/thread, 2048 blocks.
__global__ __launch_bounds__(256)
void k_fin(const short* __restrict__ p0, const short* __restrict__ p1,
           const float* __restrict__ bg, float* __restrict__ out)
{
    const int idx = (blockIdx.x * 256 + threadIdx.x) * 8;
    const int col = idx & 511;
    const bf16x8 a = *(const bf16x8*)&p0[idx];
    const bf16x8 b = *(const bf16x8*)&p1[idx];
    const f32x4 g0 = *(const f32x4*)&bg[col];
    const f32x4 g1 = *(const f32x4*)&bg[col + 4];
    f32x4 o0, o1;
#pragma unroll
    for (int e = 0; e < 4; ++e) {
        o0[e] = fmaxf(b2f(a[e]) + b2f(b[e]) + g0[e], 0.f);
        o1[e] = fmaxf(b2f(a[e + 4]) + b2f(b[e + 4]) + g1[e], 0.f);
    }
    *(f32x4*)&out[idx]     = o0;
    *(f32x4*)&out[idx + 4] = o1;
}

// =========================== helpers =======================================
// x and y cvt merged: grid(8192, 2), blockIdx.y selects stream.
__global__ __launch_bounds__(256)
void k_cvt(const float* __restrict__ x, const float* __restrict__ y,
           short* __restrict__ xb, short* __restrict__ yb)
{
    const float* in  = blockIdx.y ? y  : x;
    short*       out = blockIdx.y ? yb : xb;
    const int i = (blockIdx.x * 256 + threadIdx.x) * 4;
    const float4 v = *(const float4*)&in[i];
    bf16x4 b;
    b[0] = f2b(v.x); b[1] = f2b(v.y); b[2] = f2b(v.z); b[3] = f2b(v.w);
    *(bf16x4*)&out[i] = b;
}

__device__ __forceinline__ void transpose_body(
    const float* __restrict__ in, short* __restrict__ out, int R, int C)
{
    __shared__ short t[32][33];
    const int tx = threadIdx.x, ty = threadIdx.y;
    const int bx = blockIdx.x * 32, by = blockIdx.y * 32;
#pragma unroll
    for (int i = 0; i < 32; i += 8)
        t[ty + i][tx] = f2b(in[(size_t)(by + ty + i) * C + bx + tx]);
    __syncthreads();
#pragma unroll
    for (int i = 0; i < 32; i += 8)
        out[(size_t)(bx + ty + i) * R + by + tx] = t[tx][ty + i];
}

// Wx and Wy transposed in one launch: grid(16, 32, 2), z selects matrix.
__global__ __launch_bounds__(256)
void t_wxy(const float* __restrict__ Wx, const float* __restrict__ Wy,
           short* __restrict__ WxT, short* __restrict__ WyT)
{
    transpose_body(blockIdx.z ? Wy : Wx, blockIdx.z ? WyT : WxT, 1024, 512);
}

__global__ __launch_bounds__(256)
void t_wg(const float* __restrict__ Wg, short* __restrict__ WgT)
{
    transpose_body(Wg, WgT, 512, 512);
}

extern "C" void kernel_launch(void* const* d_in, const int* in_sizes, int n_in,
                              void* d_out, int out_size, void* d_ws, size_t ws_size,
                              hipStream_t stream)
{
    const float* x  = (const float*)d_in[0];
    const float* y  = (const float*)d_in[1];
    const float* Wx = (const float*)d_in[2];
    const float* bx = (const float*)d_in[3];
    const float* Wy = (const float*)d_in[4];
    const float* by = (const float*)d_in[5];
    const float* Wg = (const float*)d_in[6];
    const float* bg = (const float*)d_in[7];
    float* out = (float*)d_out;                // [8192, 512] f32

    char* p = (char*)d_ws;
    short* At   = (short*)p;                   // [0, 128 MB)
    short* xb   = (short*)p;                   // 16 MB, aliases At (dead by k_aff)
    short* yb   = (short*)(p + (size_t)8192 * 1024 * 2);   // next 16 MB, ditto
    p += (size_t)8192 * 8192 * 2;
    short* xpb  = (short*)p; p += (size_t)8192 * 512 * 2;
    short* ypb  = (short*)p; p += (size_t)8192 * 512 * 2;
    short* zT   = (short*)p; p += (size_t)512 * 8192 * 2;
    short* WxT  = (short*)p; p += (size_t)512 * 1024 * 2;
    short* WyT  = (short*)p; p += (size_t)512 * 1024 * 2;
    short* WgT  = (short*)p; p += (size_t)512 * 512 * 2;
    float* Dx   = (float*)p; p += (size_t)8192 * 4;
    float* Dy   = (float*)p; p += (size_t)8192 * 4;
    // split-K partials alias xpb/ypb (dead after k_aff)
    short* p0 = xpb;
    short* p1 = ypb;

    hipMemsetAsync(Dx, 0, 2 * 8192 * sizeof(float), stream);  // Dx,Dy contiguous

    dim3 tb(32, 8);
    t_wxy<<<dim3(16, 32, 2), tb, 0, stream>>>(Wx, Wy, WxT, WyT);
    t_wg<<<dim3(16, 16), tb, 0, stream>>>(Wg, WgT);

    k_cvt<<<dim3(8192, 2), 256, 0, stream>>>(x, y, xb, yb);

    k_proj<<<dim3(8, 128), 256, 0, stream>>>(xb, WxT, bx, xpb, Dx);
    k_proj<<<dim3(8, 128), 256, 0, stream>>>(yb, WyT, by, ypb, Dy);

    k_zT<<<dim3(128, 8), 256, 0, stream>>>(WgT, xpb, zT);

    k_aff<<<4096, 256, 0, stream>>>(ypb, xpb, At, Dy, Dx);

    k_agg<<<512, 256, 0, stream>>>(At, zT, p0, p1);

    k_fin<<<2048, 256, 0, stream>>>(p0, p1, bg, out);
}